// Round 3
// baseline (541.357 us; speedup 1.0000x reference)
//
#include <hip/hip_runtime.h>

// RelativePositionEncoding (AF3-style), B=1, N=1024, C_Z=128. HBM-write-bound:
// 537 MB out, write roofline ~85 us @ 6.3 TB/s. Harness adds ~425 us/iter of
// poison-fill overhead (2 GiB d_ws + 537 MB d_out) visible in rocprof.
//
// R8 = R7 with SEQUENTIAL per-wave store streams. A/B history: R5 (fused
// 405 KB table + nt stores) 533.3, R6 (split tables + nt) 533.6, R7 (split
// tables + plain) 534.7 -> gather footprint and store type are both
// non-factors. Remaining difference vs the 6.3 TB/s fill kernel: K2's wave
// wrote 1024 B then jumped 4 KB (jj interleaved by 8), scattering TCC
// write-combining / HBM page locality. Now each wave owns a contiguous
// 128-row (64 KB) chunk of the j-tile: store stream is fully sequential
// 1024 B-after-1024 B, matching the fill's access shape.
//
// Table layout (verified absmax=0 in R6/R7):
//   Pos[132][128] (67.6 KB, ws): row<66: W_pos[32]+W_tok[row] (same chain+res)
//                                row>=66: W_pos[row-66]+W_tok[65]
//   Ch[6][128]    (3 KB, LDS):   c<5: W_ch[c]+w_ent (same ent); c=5: W_ch[5]
// out[i,j,:] = Pos[row] + Ch[crow]; association (Wp+Wt)+(Wch+went) unchanged
// -> bitwise-identical output.

#define RMAX 32
#define SMAX 2
#define TJ 512
#define BLOCK 256

typedef float v4f __attribute__((ext_vector_type(4)));

// ---- K1: build Pos[132][128] then Ch[6][128] contiguously in d_ws ----
__global__ __launch_bounds__(BLOCK) void build_tables(
    const float* __restrict__ W, v4f* __restrict__ T)
{
    const int t = blockIdx.x * BLOCK + threadIdx.x;
    if (t >= 138 * 32) return;
    const int rc = t >> 5;          // table row 0..137 (132 Pos + 6 Ch)
    const int cc = t & 31;          // float4 group 0..31

    const v4f* __restrict__ W4 = reinterpret_cast<const v4f*>(W);
    // W rows: W_pos 0..65, W_tok 66..131, w_ent 132, W_ch 133..138.
    v4f o;
    if (rc < 66) {
        o = W4[32 * 32 + cc] + W4[(66 + rc) * 32 + cc];
    } else if (rc < 132) {
        o = W4[(rc - 66) * 32 + cc] + W4[131 * 32 + cc];
    } else {
        const int c = rc - 132;     // 0..5
        if (c < 5) o = W4[(133 + c) * 32 + cc] + W4[132 * 32 + cc];
        else       o = W4[138 * 32 + cc];
    }
    T[rc * 32 + cc] = o;
}

// ---- K2: stream the output; per-wave contiguous 64 KB store streams ----
__global__ __launch_bounds__(BLOCK) void relpos_stream(
    const int* __restrict__ asym, const int* __restrict__ resi,
    const int* __restrict__ ent,  const int* __restrict__ sym,
    const int* __restrict__ tok,  const char* __restrict__ Tbytes,
    float* __restrict__ out, int N)
{
    __shared__ int sAddr[TJ];       // per-j packed (row*512 | crow<<20), 2 KB
    __shared__ v4f sCh[6 * 32];     // 6 ch rows x 512 B = 3 KB

    const int tid = threadIdx.x;
    const int i   = blockIdx.y;
    const int j0  = blockIdx.x * TJ;

    // stage the 6 ch rows into LDS (Ch lives at byte 132*512 in T)
    if (tid < 192)
        sCh[tid] = *reinterpret_cast<const v4f*>(Tbytes + 132 * 512 + (tid << 4));

    // --- index build: packed offsets for this j-tile ---
    const int ai = asym[i], ri = resi[i], ei = ent[i], si = sym[i], ti = tok[i];
    for (int t = tid; t < TJ; t += BLOCK) {
        const int j = j0 + t;
        const int aj = asym[j], rj = resi[j], ej = ent[j], sj = sym[j], tj = tok[j];
        int row;
        if (ai == aj) {
            if (ri == rj) {
                int dt = ti - tj + RMAX;
                dt = dt < 0 ? 0 : (dt > 2 * RMAX ? 2 * RMAX : dt);
                row = dt;
            } else {
                int dr = ri - rj + RMAX;
                dr = dr < 0 ? 0 : (dr > 2 * RMAX ? 2 * RMAX : dr);
                row = 66 + dr;
            }
        } else {
            row = 131;
        }
        int crow;
        if (ei == ej) {
            int dc = si - sj + SMAX;
            dc = dc < 0 ? 0 : (dc > 2 * SMAX ? 2 * SMAX : dc);
            crow = dc;
        } else {
            crow = 5;
        }
        sAddr[t] = (row << 9) | (crow << 20);   // row*512 bytes | ch row id
    }
    __syncthreads();

    // --- stream: wave w owns rows [w*128, w*128+128) -> sequential 64 KB ---
    const int lane = tid & 63;
    const int w    = tid >> 6;      // wave 0..3
    const int cc   = lane & 31;     // float4 group within row
    const int half = lane >> 5;     // 0/1: which of the pair of rows
    v4f* __restrict__ out4 = reinterpret_cast<v4f*>(out);
    const size_t base = ((size_t)i * N + j0) * 32 + cc;

    #pragma unroll 8
    for (int it = 0; it < 64; ++it) {
        const int jj = (w << 7) + (it << 1) + half;
        const int a = sAddr[jj];
        const v4f p = *reinterpret_cast<const v4f*>(
            Tbytes + (a & 0xFFFFF) + (cc << 4));
        out4[base + (size_t)jj * 32] = p + sCh[((a >> 20) << 5) + cc];
    }
}

extern "C" void kernel_launch(void* const* d_in, const int* in_sizes, int n_in,
                              void* d_out, int out_size, void* d_ws, size_t ws_size,
                              hipStream_t stream) {
    const int* asym = (const int*)d_in[0];
    const int* resi = (const int*)d_in[1];
    const int* ent  = (const int*)d_in[2];
    const int* sym  = (const int*)d_in[3];
    const int* tok  = (const int*)d_in[4];
    const float* W  = (const float*)d_in[5];
    float* out = (float*)d_out;

    const int N = in_sizes[0];          // B*N with B=1 (N=1024)

    // K1: 138 rows * 32 float4 = 4416 threads -> 18 blocks
    build_tables<<<18, BLOCK, 0, stream>>>(W, (v4f*)d_ws);

    // K2: (j-tile, i) grid; same-stream ordering makes T visible to K2
    dim3 grid(N / TJ, N);
    relpos_stream<<<grid, BLOCK, 0, stream>>>(
        asym, resi, ent, sym, tok, (const char*)d_ws, out, N);
}

// Round 4
// 531.929 us; speedup vs baseline: 1.0177x; 1.0177x over previous
//
#include <hip/hip_runtime.h>

// RelativePositionEncoding (AF3-style), B=1, N=1024, C_Z=128. HBM-write-bound:
// 537 MB out, write roofline ~85 us @ 6.3 TB/s. Harness adds ~425 us/iter of
// poison-fill overhead (2 GiB d_ws + 537 MB d_out) visible in rocprof.
//
// R9 = exact revert to R5 (best measured: 532.9 us). Session A/B ledger:
//   R5 fused-table + nt + interleaved stores      532.9  <- this kernel
//   R6 split-table + nt + interleaved             533.6  (gather footprint: nil)
//   R7 split-table + plain + interleaved          534.7  (store type: nil)
//   R8 split-table + plain + per-wave sequential  541.4  (REGRESSION: lost
//      inter-wave merged bursts; interleave IS the good store shape)
// K2 ~105 us = 5.1 TB/s vs 6.3 TB/s pure-write: the ~19% residual survived
// all four mechanism hypotheses -> cost of the dependent gather+add+store
// chain; structural floor ~513 us (425 fills + 85 write + 3 misc).
//
// Fused-table algebra (verified absmax=0): out[i,j,:] = C[row*6 + crow],
//   row  < 66 : W_pos[32]  + W_tok[row]        (same chain+res, dt=row)
//   row >= 66 : W_pos[row-66] + W_tok[65]      (dr = row-66; diff chain -> 131)
//   crow < 5  : W_ch[crow] + w_ent             (same entity)
//   crow == 5 : W_ch[5]

#define RMAX 32
#define SMAX 2
#define TJ 512
#define BLOCK 256

typedef float v4f __attribute__((ext_vector_type(4)));

// ---- K1: build the 792 x 128 combined-row table in d_ws ----
__global__ __launch_bounds__(BLOCK) void build_combo(
    const float* __restrict__ W, float4* __restrict__ C)
{
    const int t  = blockIdx.x * BLOCK + threadIdx.x;
    const int rc = t >> 5;          // combined row 0..791
    const int cc = t & 31;          // float4 group 0..31
    const int r  = rc / 6;          // 0..131
    const int c  = rc - r * 6;      // 0..5

    const float4* __restrict__ W4 = reinterpret_cast<const float4*>(W);
    // W rows: W_pos 0..65, W_tok 66..131, w_ent 132, W_ch 133..138.
    float4 a, b;
    if (r < 66) { a = W4[32 * 32 + cc];       b = W4[(66 + r) * 32 + cc]; }
    else        { a = W4[(r - 66) * 32 + cc]; b = W4[131 * 32 + cc];      }
    float4 d;
    if (c < 5) {
        const float4 e = W4[(133 + c) * 32 + cc];
        const float4 f = W4[132 * 32 + cc];
        d = make_float4(e.x + f.x, e.y + f.y, e.z + f.z, e.w + f.w);
    } else {
        d = W4[138 * 32 + cc];
    }
    C[rc * 32 + cc] = make_float4(a.x + b.x + d.x, a.y + b.y + d.y,
                                  a.z + b.z + d.z, a.w + b.w + d.w);
}

// ---- K2: stream the output; pure gather-memcpy hot loop, nt stores ----
__global__ __launch_bounds__(BLOCK) void relpos_stream(
    const int* __restrict__ asym, const int* __restrict__ resi,
    const int* __restrict__ ent,  const int* __restrict__ sym,
    const int* __restrict__ tok,  const char* __restrict__ Cbytes,
    float* __restrict__ out, int N)
{
    __shared__ int sAddr[TJ];      // per-j byte offset into C (2 KB)

    const int tid = threadIdx.x;
    const int i   = blockIdx.y;
    const int j0  = blockIdx.x * TJ;

    // --- index build: (row*6+crow)*512 byte offsets for this j-tile ---
    const int ai = asym[i], ri = resi[i], ei = ent[i], si = sym[i], ti = tok[i];
    for (int t = tid; t < TJ; t += BLOCK) {
        const int j = j0 + t;
        const int aj = asym[j], rj = resi[j], ej = ent[j], sj = sym[j], tj = tok[j];
        int row;
        if (ai == aj) {
            if (ri == rj) {
                int dt = ti - tj + RMAX;
                dt = dt < 0 ? 0 : (dt > 2 * RMAX ? 2 * RMAX : dt);
                row = dt;
            } else {
                int dr = ri - rj + RMAX;
                dr = dr < 0 ? 0 : (dr > 2 * RMAX ? 2 * RMAX : dr);
                row = 66 + dr;
            }
        } else {
            row = 131;
        }
        int crow;
        if (ei == ej) {
            int dc = si - sj + SMAX;
            dc = dc < 0 ? 0 : (dc > 2 * SMAX ? 2 * SMAX : dc);
            crow = dc;
        } else {
            crow = 5;
        }
        sAddr[t] = (row * 6 + crow) << 9;   // *512 bytes per combined row
    }
    __syncthreads();

    // --- stream: wave = 2 rows x 512 B = contiguous 1024 B nt stores ---
    const int cc = tid & 31;   // float4 group within row
    const int jl = tid >> 5;   // 0..7
    v4f* __restrict__ out4 = reinterpret_cast<v4f*>(out);
    const size_t base = ((size_t)i * N + j0) * 32 + cc;

    #pragma unroll 8
    for (int jj = jl; jj < TJ; jj += 8) {
        const int off = sAddr[jj];
        const v4f v = *reinterpret_cast<const v4f*>(Cbytes + off + (cc << 4));
        __builtin_nontemporal_store(v, out4 + base + (size_t)jj * 32);
    }
}

extern "C" void kernel_launch(void* const* d_in, const int* in_sizes, int n_in,
                              void* d_out, int out_size, void* d_ws, size_t ws_size,
                              hipStream_t stream) {
    const int* asym = (const int*)d_in[0];
    const int* resi = (const int*)d_in[1];
    const int* ent  = (const int*)d_in[2];
    const int* sym  = (const int*)d_in[3];
    const int* tok  = (const int*)d_in[4];
    const float* W  = (const float*)d_in[5];
    float* out = (float*)d_out;

    const int N = in_sizes[0];          // B*N with B=1 (N=1024)

    // K1: 792 rows * 32 float4 = 25344 threads = 99 blocks
    build_combo<<<99, BLOCK, 0, stream>>>(W, (float4*)d_ws);

    // K2: (j-tile, i) grid; same-stream ordering makes C visible to K2
    dim3 grid(N / TJ, N);
    relpos_stream<<<grid, BLOCK, 0, stream>>>(
        asym, resi, ent, sym, tok, (const char*)d_ws, out, N);
}